// Round 6
// baseline (1203.656 us; speedup 1.0000x reference)
//
#include <hip/hip_runtime.h>
#include <cstdint>

#define T_STEPS 128
#define BATCH   1024
#define D_INPUT 96
#define H_DIM   128
#define NWIN    163   // 121 full 7-frame windows + 6 prefix partials + 36 clipped partials
#define BD      (BATCH * D_INPUT)   // 98304 floats per time frame

// (t, s) -> widx, or -1 when the reference window is empty (cur1 == +0)
__device__ __forceinline__ int widx_for(int t, int s) {
    if (t >= 49) return t - 49 + 7 * s;                 // slide regime: full windows
    if (s == 0)  return 121 + min(5, t);                // [0, min(5,t)]
    const int st = 7 * s - 1;
    if (t < st) return -1;
    const int len = min(7, t - st + 1);
    return (len == 7) ? st : (127 + (s - 1) * 6 + (len - 1));
}

// ---------------------------------------------------------------------------
// kT: one-shot weight reshapes.
//   blocks 0..47  : Win (128x96)  -> WinT (96x128)
//   blocks 48..111: Wh0 (128x128) -> Wh0O packed 64 B per (j, i-octet q):
//     Wh0O[(j*16+q)*16 + p*8 + r] = Wh0[(8q+r)*128 + (2j+p)]
//   kB's lane (i-octet q) fetches its 16 weights for h-pair j as FOUR
//   float4 loads from ONE 64-B line (line count per j unchanged vs r5).
// ---------------------------------------------------------------------------
__global__ __launch_bounds__(256) void kT_wint(const float* __restrict__ Win,
                                               const float* __restrict__ Wh0,
                                               float* __restrict__ WinT,
                                               float* __restrict__ Wh0O) {
    const int tid = threadIdx.x;
    if (blockIdx.x < 48) {
        const int e = blockIdx.x * 256 + tid;           // < 128*96
        const int h = e / D_INPUT, d = e % D_INPUT;
        WinT[d * H_DIM + h] = Win[e];
    } else {
        const int e = (blockIdx.x - 48) * 256 + tid;    // < 64*16*16 = 16384
        const int r = e & 7, p = (e >> 3) & 1, q = (e >> 4) & 15, j = e >> 8;
        Wh0O[e] = Wh0[(8 * q + r) * H_DIM + (2 * j + p)];
    }
}

// ---------------------------------------------------------------------------
// kA0: one streaming pass over x. Thread <-> (b,d); 7-frame ring in registers
// (t-loop fully unrolled -> all ring indices compile-time -> no scratch).
// Emits every window sum with the EXACT ascending-frame __fadd_rn chain.
// UNCHANGED this round.
// ---------------------------------------------------------------------------
__global__ __launch_bounds__(256) void kA0_winsum(const float* __restrict__ x,
                                                  float* __restrict__ WS) {
    const int flat = blockIdx.x * 256 + threadIdx.x;    // b*96 + d
    float* wsp = WS + flat;
    float r[7];
#pragma unroll
    for (int t = 0; t < T_STEPS; ++t) {
        r[t % 7] = x[(size_t)t * BD + flat];
        if (t <= 5) {                                   // s0 prefix, len = t+1
            float s = r[0];
#pragma unroll
            for (int k = 1; k <= t; ++k) s = __fadd_rn(s, r[k % 7]);
            wsp[(size_t)(121 + t) * BD] = s;
        }
        if (t >= 6 && t <= 126) {                       // full window w = t-6
            const int w = t - 6;
            float s = r[w % 7];
#pragma unroll
            for (int k = 1; k < 7; ++k) s = __fadd_rn(s, r[(w + k) % 7]);
            wsp[(size_t)w * BD] = s;
        }
        if (t >= 6 && t <= 46) {                        // grow partial (<=1 per t)
            const int sv = (t + 1) / 7;
            if (sv >= 1 && 7 * sv >= t - 4 && 7 * sv <= t + 1) {
                const int start = 7 * sv - 1;
                const int len = t - start + 1;          // 1..6 by construction
                float s = r[start % 7];
#pragma unroll
                for (int k = 1; k < len; ++k) s = __fadd_rn(s, r[(start + k) % 7]);
                wsp[(size_t)(127 + (sv - 1) * 6 + (len - 1)) * BD] = s;
            }
        }
    }
}

// ---------------------------------------------------------------------------
// kA1 (round-6): 64-b tile, lane = (h-quad q, b-octet). Per d per lane:
//   2x conflict-free b64 weight reads (pair-split wq layout: even h-pairs at
//   words 0..63, odd at 64..127 -> banks exactly 2-way = free) +
//   2x broadcast float4 window-sum reads -> 32 fma (was 30 LDS-cyc / 16 fma).
// Per-b LDS demand drops 1.7x. xs swizzled by ^(d&24) (float4-preserving;
// staging writes 8-way instead of 32-way). Per-(b,h) chain is the SAME
// ascending-d single-acc fma chain -> CUR1 bit-identical.
// LDS 72 KB -> 2 blocks/CU (8 waves).
// ---------------------------------------------------------------------------
__global__ __launch_bounds__(256) void kA_wincur(const float* __restrict__ WS,
                                                 const float* __restrict__ WinT,
                                                 float* __restrict__ CUR1) {
    __shared__ float xs[D_INPUT * 64];                  // 24 KB, xs[d*64 + (bq^(d&24))]
    __shared__ float wq[D_INPUT * H_DIM];               // 48 KB, pair-split per row
    const int widx = blockIdx.x;
    const int b0   = blockIdx.y * 64;
    const int tid  = threadIdx.x;

    // stage weights: pair p=(h>>1) of row d at word ((p&1)<<6) + ((p>>1)<<1)
    {
        const float2* WinT2 = (const float2*)WinT;
        for (int e2 = tid; e2 < D_INPUT * 64; e2 += 256) {
            const int p = e2 & 63, d = e2 >> 6;
            *(float2*)&wq[d * 128 + ((p & 1) << 6) + ((p >> 1) << 1)] = WinT2[e2];
        }
    }
    // stage window sums (coalesced global read; 8-way swizzled LDS write)
    for (int e = tid; e < D_INPUT * 64; e += 256) {
        const int d = e % 96, bq = e / 96;
        xs[d * 64 + (bq ^ (d & 24))] =
            WS[(size_t)widx * BD + (size_t)(b0 + bq) * 96 + d];
    }
    __syncthreads();

    const int q  = tid & 31;                            // h-quad (4 h's)
    const int g  = (tid >> 5) & 1;
    const int w  = tid >> 6;
    const int ob = (w << 1) | g;                        // b-octet 0..7

    float acc[8][4];
#pragma unroll
    for (int r = 0; r < 8; ++r)
#pragma unroll
        for (int hh = 0; hh < 4; ++hh) acc[r][hh] = 0.f;

#pragma unroll 4
    for (int d = 0; d < D_INPUT; ++d) {
        const float2 wp0 = *(const float2*)&wq[d * 128 + 2 * q];       // h=4q,4q+1
        const float2 wp1 = *(const float2*)&wq[d * 128 + 64 + 2 * q];  // h=4q+2,4q+3
        const int xb = d * 64 + ((ob * 8) ^ (d & 24));
        const float4 xv0 = *(const float4*)&xs[xb];
        const float4 xv1 = *(const float4*)&xs[xb + 4];
        const float xv[8] = {xv0.x,xv0.y,xv0.z,xv0.w, xv1.x,xv1.y,xv1.z,xv1.w};
#pragma unroll
        for (int r = 0; r < 8; ++r) {
            acc[r][0] = __fmaf_rn(xv[r], wp0.x, acc[r][0]);
            acc[r][1] = __fmaf_rn(xv[r], wp0.y, acc[r][1]);
            acc[r][2] = __fmaf_rn(xv[r], wp1.x, acc[r][2]);
            acc[r][3] = __fmaf_rn(xv[r], wp1.y, acc[r][3]);
        }
    }
    float* op = CUR1 + ((size_t)widx * BATCH + b0 + ob * 8) * H_DIM + 4 * q;
#pragma unroll
    for (int r = 0; r < 8; ++r) {
        float4 o; o.x = acc[r][0]; o.y = acc[r][1]; o.z = acc[r][2]; o.w = acc[r][3];
        *(float4*)(op + (size_t)r * H_DIM) = o;
    }
}

// ---------------------------------------------------------------------------
// kB: 7 SNN steps, 16 (t,b) pairs per wave.
// ROUND-6 CHANGE (r5 lesson: LDS-instr cuts at zero VALU cost pay ~1:1).
// cur2 lane remap (4i x 8b) -> (8i x 4b): lane = (g2 = b-quad, q = i-octet).
// Per j per lane: spikes = TWO b128 (one 16-B se-quad chunk + one so chunk;
// was 4), weights = FOUR float4 from one 64-B line of Wh0O (same unique
// line count as r5), fma = 64 (unchanged, raw f32 spikes). LDS/CU-round
// 768 -> 384 < VALU 512 -> VALU becomes the limiter. Per-(b,i) chain is
// the same ascending-h single-acc fma chain -> bit-identical spike stream.
// mem1 phase, publish layout/swizzle, c1 prefetch: r5-verbatim.
// ---------------------------------------------------------------------------
__global__ __launch_bounds__(512, 2) void kB_snn(const float* __restrict__ CUR1,
                                                 const float* __restrict__ Wh0O,
                                                 const float* __restrict__ Wout,
                                                 const float* __restrict__ vxp,
                                                 const float* __restrict__ vyp,
                                                 float* __restrict__ out) {
    __shared__ float sf[8][64 * 32];                    // 64 KB, per-wave spike floats
    const int tid = threadIdx.x;

    const int w = tid >> 6, lane = tid & 63;
    const int t  = blockIdx.y;
    const int i0 = lane << 1;                           // mem1 h-pair (unchanged role)
    const int g2 = lane >> 4;                           // cur2: b-quad 0..3
    const int q  = lane & 15;                           // cur2: i-octet 0..15
    float* sfw = sf[w];
    const int lbase = lane * 32;                        // publish strip (h-pair = lane)
    const float4 wea = *(const float4*)&Wout[q * 8];
    const float4 web = *(const float4*)&Wout[q * 8 + 4];
    const float4 woa = *(const float4*)&Wout[H_DIM + q * 8];
    const float4 wob = *(const float4*)&Wout[H_DIM + q * 8 + 4];
    const float wex[8] = {wea.x,wea.y,wea.z,wea.w, web.x,web.y,web.z,web.w};
    const float wey[8] = {woa.x,woa.y,woa.z,woa.w, wob.x,wob.y,wob.z,wob.w};
    const float vx = vxp[0], vy = vyp[0];
    const int b0 = (blockIdx.x << 7) + (w << 4);        // 16 consecutive b per wave
    const float* wbase = Wh0O + q * 16;                 // this lane's weight line

    float m1a[16], m1b[16], c1a[16], c1b[16];
    bool  s1a[16], s1b[16];
    float m2[4][8], po0[4], po1[4];
    bool  s2[4][8];
#pragma unroll
    for (int k = 0; k < 16; ++k) {
        m1a[k]=0.f; m1b[k]=0.f; s1a[k]=false; s1b[k]=false;
    }
#pragma unroll
    for (int b = 0; b < 4; ++b) {
        po0[b]=0.f; po1[b]=0.f;
#pragma unroll
        for (int r = 0; r < 8; ++r) { m2[b][r]=0.f; s2[b][r]=false; }
    }

    // load cur1 for s = 0
    {
        const int wi = widx_for(t, 0);
#pragma unroll
        for (int k = 0; k < 16; ++k) {
            c1a[k] = 0.f; c1b[k] = 0.f;
            if (wi >= 0) {
                const float2 v = *(const float2*)
                    &CUR1[((size_t)wi * BATCH + b0 + k) * H_DIM + i0];
                c1a[k] = v.x; c1b[k] = v.y;
            }
        }
    }

#pragma unroll 1
    for (int s = 0; s < 7; ++s) {
        // ---- mem1 update + spike floats (exact), publish to sf -------------
        float sev[16], sov[16];
#pragma unroll
        for (int k = 0; k < 16; ++k) {
            m1a[k] = s1a[k] ? 0.f : __fadd_rn(__fmul_rn(0.9f, m1a[k]), c1a[k]);
            m1b[k] = s1b[k] ? 0.f : __fadd_rn(__fmul_rn(0.9f, m1b[k]), c1b[k]);
            s1a[k] = m1a[k] > 0.5f; s1b[k] = m1b[k] > 0.5f;
            sev[k] = s1a[k] ? 1.0f : 0.0f;
            sov[k] = s1b[k] ? 1.0f : 0.0f;
        }
        // chunks 0..3 = se quads, 4..7 = so quads; chunk swizzled by lane&7
#pragma unroll
        for (int c = 0; c < 4; ++c) {
            float4 v;
            v.x = sev[c*4]; v.y = sev[c*4+1]; v.z = sev[c*4+2]; v.w = sev[c*4+3];
            *(float4*)&sfw[lbase + ((c     ^ (lane & 7)) << 2)] = v;
            v.x = sov[c*4]; v.y = sov[c*4+1]; v.z = sov[c*4+2]; v.w = sov[c*4+3];
            *(float4*)&sfw[lbase + (((c+4) ^ (lane & 7)) << 2)] = v;
        }

        // ---- prefetch next step's cur1 into the now-dead c1 registers ------
        const int win = (s < 6) ? widx_for(t, s + 1) : -1;
#pragma unroll
        for (int k = 0; k < 16; ++k) {
            c1a[k] = 0.f; c1b[k] = 0.f;
            if (win >= 0) {
                const float2 v = *(const float2*)
                    &CUR1[((size_t)win * BATCH + b0 + k) * H_DIM + i0];
                c1a[k] = v.x; c1b[k] = v.y;
            }
        }

        // ---- dense cur2: ascending h; 2 broadcast b128 + 4 float4 VMEM / j -
        float c2[4][8];
#pragma unroll
        for (int b = 0; b < 4; ++b)
#pragma unroll
            for (int r = 0; r < 8; ++r) c2[b][r] = 0.f;

#pragma unroll 8
        for (int j = 0; j < 64; ++j) {
            const float* wj = wbase + (size_t)j * 256;
            const float4 wa = *(const float4*)&wj[0];   // h=2j,   i = 8q..8q+3
            const float4 wb = *(const float4*)&wj[4];   // h=2j,   i = 8q+4..8q+7
            const float4 wc = *(const float4*)&wj[8];   // h=2j+1, i = 8q..8q+3
            const float4 wd = *(const float4*)&wj[12];  // h=2j+1, i = 8q+4..8q+7
            const int jb = j * 32, js = j & 7;
            const float4 E = *(const float4*)&sfw[jb + (((g2    ) ^ js) << 2)];
            const float4 O = *(const float4*)&sfw[jb + (((g2 + 4) ^ js) << 2)];
            const float seb[4] = {E.x, E.y, E.z, E.w};
            const float sob[4] = {O.x, O.y, O.z, O.w};
            const float wev[8] = {wa.x,wa.y,wa.z,wa.w, wb.x,wb.y,wb.z,wb.w};
            const float wov[8] = {wc.x,wc.y,wc.z,wc.w, wd.x,wd.y,wd.z,wd.w};
#pragma unroll
            for (int b = 0; b < 4; ++b) {
#pragma unroll
                for (int r = 0; r < 8; ++r) {
                    c2[b][r] = __fmaf_rn(seb[b], wev[r], c2[b][r]);   // h = 2j
                    c2[b][r] = __fmaf_rn(sob[b], wov[r], c2[b][r]);   // h = 2j+1
                }
            }
        }

        // ---- mem2 + spikes (exact) and linear output tail (relaxed) --------
#pragma unroll
        for (int b = 0; b < 4; ++b) {
            float p0 = 0.f, p1 = 0.f;
#pragma unroll
            for (int r = 0; r < 8; ++r) {
                m2[b][r] = s2[b][r] ? 0.f
                         : __fadd_rn(__fmul_rn(0.9f, m2[b][r]), c2[b][r]);
                s2[b][r] = m2[b][r] > 0.5f;
                p0 += s2[b][r] ? wex[r] : 0.f;
                p1 += s2[b][r] ? wey[r] : 0.f;
            }
            po0[b] = __fmaf_rn(0.9f, po0[b], p0);       // mem_out linear: order-safe
            po1[b] = __fmaf_rn(0.9f, po1[b], p1);
        }
    }

    // ---- reduce per-lane output partials over the 16-lane i-groups ----------
#pragma unroll
    for (int b = 0; b < 4; ++b) {
        float r0 = po0[b], r1 = po1[b];
#pragma unroll
        for (int off = 8; off > 0; off >>= 1) {
            r0 += __shfl_xor(r0, off);
            r1 += __shfl_xor(r1, off);
        }
        if (q == 0) {
            float2 o;
            o.x = __fmul_rn(r0, vx);
            o.y = __fmul_rn(r1, vy);
            *(float2*)(out + ((size_t)t * BATCH + b0 + g2 * 4 + b) * 2) = o;
        }
    }
}

// ---------------------------------------------------------------------------
extern "C" void kernel_launch(void* const* d_in, const int* in_sizes, int n_in,
                              void* d_out, int out_size, void* d_ws, size_t ws_size,
                              hipStream_t stream) {
    const float* x    = (const float*)d_in[0];   // (128,1024,96)
    const float* Win  = (const float*)d_in[1];   // (128,96)
    const float* Wh0  = (const float*)d_in[2];   // (128,128)
    const float* Wout = (const float*)d_in[3];   // (2,128)
    const float* vx   = (const float*)d_in[4];   // (1,)
    const float* vy   = (const float*)d_in[5];   // (1,)
    float* out  = (float*)d_out;                 // (128,1024,2)

    // workspace: CUR1 (85.5 MB) | WS (64.1 MB) | WinT (48 KB) | Wh0O (64 KB)
    float* CUR1 = (float*)d_ws;
    float* WS   = CUR1 + (size_t)NWIN * BATCH * H_DIM;
    float* WinT = WS   + (size_t)NWIN * BATCH * D_INPUT;
    float* Wh0O = WinT + (size_t)D_INPUT * H_DIM;

    kT_wint   <<<dim3(112),                  dim3(256), 0, stream>>>(Win, Wh0, WinT, Wh0O);
    kA0_winsum<<<dim3(BD / 256),             dim3(256), 0, stream>>>(x, WS);
    kA_wincur <<<dim3(NWIN, BATCH / 64),     dim3(256), 0, stream>>>(WS, WinT, CUR1);
    kB_snn    <<<dim3(BATCH / 128, T_STEPS), dim3(512), 0, stream>>>(CUR1, Wh0O, Wout, vx, vy, out);
}